// Round 2
// baseline (352.992 us; speedup 1.0000x reference)
//
#include <hip/hip_runtime.h>
#include <hip/hip_bf16.h>

typedef __bf16 bf16x8 __attribute__((ext_vector_type(8)));
typedef float  f32x4  __attribute__((ext_vector_type(4)));
typedef float  float4v __attribute__((ext_vector_type(4)));
typedef short  short4v __attribute__((ext_vector_type(4)));

#define BM 128
#define BN 128
#define BKK 64

static constexpr int Tn   = 2048;
static constexpr int Bn   = 16;
static constexpr int Cn   = 768;
static constexpr int NQK  = 2 * Cn;  // 1536 (Q and K only; V is algebraically eliminated)

__device__ __forceinline__ void gload_lds16(const void* g, void* l) {
  __builtin_amdgcn_global_load_lds((const __attribute__((address_space(1))) void*)g,
                                   (__attribute__((address_space(3))) void*)l, 16, 0, 0);
}

// stage a 128x64 bf16 tile (row-major in LDS, global row stride = 768 bf16)
__device__ __forceinline__ void stage_tile(const char* gbase, __bf16* lds, int t) {
#pragma unroll
  for (int i = 0; i < 4; ++i) {
    int O   = i * 4096 + t * 16;
    int row = O >> 7;     // 128 bytes per LDS row
    int cb  = O & 127;
    gload_lds16(gbase + (size_t)row * 1536 + cb, (char*)lds + O);
  }
}

// ---------------- fused QK projection: C1[m][n] = sum_c X[m][c]*W[n][c] + bias[n]
__global__ __launch_bounds__(256, 2)
void proj_kernel(const __bf16* __restrict__ X, const __bf16* __restrict__ W,
                 const float* __restrict__ bias,
                 __hip_bfloat16* __restrict__ Q, __hip_bfloat16* __restrict__ Kb)
{
  __shared__ __bf16 smem[2 * BM * BKK];   // 32 KiB; reused as C-tile in epilogue
  __bf16* As = smem;
  __bf16* Bs = smem + BM * BKK;

  const int t = threadIdx.x;
  // XCD-chunked swizzle: nwg = 12*256 = 3072, divisible by 8
  int flat = blockIdx.x + 12 * blockIdx.y;
  flat = (flat & 7) * 384 + (flat >> 3);
  const int tile_n = (flat % 12) * BN;
  const int tile_m = (flat / 12) * BM;

  const int lane   = t & 63;
  const int wv     = t >> 6;
  const int wm     = wv >> 1, wn = wv & 1;
  const int lrow   = lane & 15;
  const int lk8    = (lane >> 4) * 8;

  const char* Ab = (const char*)(X + (size_t)tile_m * Cn);
  const char* Bb = (const char*)(W + (size_t)tile_n * Cn);

  f32x4 acc[4][4] = {};

  for (int k0 = 0; k0 < Cn; k0 += BKK) {
    stage_tile(Ab + (size_t)k0 * 2, As, t);
    stage_tile(Bb + (size_t)k0 * 2, Bs, t);
    __syncthreads();
#pragma unroll
    for (int ks = 0; ks < 2; ++ks) {
      bf16x8 a[4], b[4];
#pragma unroll
      for (int mi = 0; mi < 4; ++mi)
        a[mi] = *(const bf16x8*)&As[(wm * 64 + mi * 16 + lrow) * BKK + ks * 32 + lk8];
#pragma unroll
      for (int ni = 0; ni < 4; ++ni)
        b[ni] = *(const bf16x8*)&Bs[(wn * 64 + ni * 16 + lrow) * BKK + ks * 32 + lk8];
#pragma unroll
      for (int mi = 0; mi < 4; ++mi)
#pragma unroll
        for (int ni = 0; ni < 4; ++ni)
          acc[mi][ni] = __builtin_amdgcn_mfma_f32_16x16x32_bf16(a[mi], b[ni], acc[mi][ni], 0, 0, 0);
    }
    __syncthreads();
  }

  // epilogue: add bias, repack through LDS (lightly swizzled), coalesced bf16x8 stores
  const int which = tile_n / Cn;                 // 0 -> Q, 1 -> K
  const int nbase = tile_n - which * Cn;
  __bf16* outw = (__bf16*)(which ? Kb : Q);
  const int crow = (lane >> 4) * 4;
  __bf16* ct = smem;                             // [128][128]
#pragma unroll
  for (int ni = 0; ni < 4; ++ni) {
    const int coff = wn * 64 + ni * 16 + lrow;
    const float bb = bias[tile_n + coff];
#pragma unroll
    for (int mi = 0; mi < 4; ++mi) {
      const int rbase = wm * 64 + mi * 16 + crow;
#pragma unroll
      for (int r = 0; r < 4; ++r) {
        const int row = rbase + r;
        const int g   = ((coff >> 3) ^ (((row >> 2) & 1) << 2)) << 3;  // 16B-granule XOR swizzle
        ct[row * 128 + g + (coff & 7)] = (__bf16)(acc[mi][ni][r] + bb);
      }
    }
  }
  __syncthreads();
  const int rcol = (t & 15) * 8;
#pragma unroll
  for (int p = 0; p < 8; ++p) {
    const int row = p * 16 + (t >> 4);
    const int g   = ((rcol >> 3) ^ (((row >> 2) & 1) << 2)) << 3;
    bf16x8 v = *(const bf16x8*)&ct[row * 128 + g];
    *(bf16x8*)(outw + (size_t)(tile_m + row) * Cn + nbase + rcol) = v;
  }
}

// ---------------- attention colsum: w[b,k'] += sum_q sigmoid(scale * Q_q . K_k')
__global__ __launch_bounds__(256, 2)
void attn_kernel(const __bf16* __restrict__ Q, const __bf16* __restrict__ K,
                 float* __restrict__ wsum)
{
  __shared__ __bf16 smem[2 * BM * BKK];
  __bf16* As = smem;
  __bf16* Bs = smem + BM * BKK;

  const int t = threadIdx.x;
  // XCD-chunked swizzle: nwg = 16*16*16 = 4096, divisible by 8.
  // After swizzle each XCD owns ~2 consecutive batches -> K panel (3 MB) L2-resident.
  int flat = blockIdx.x + (blockIdx.y << 4) + (blockIdx.z << 8);
  flat = (flat & 7) * 512 + (flat >> 3);
  const int kt = flat & 15;
  const int qt = (flat >> 4) & 15;
  const int b  = flat >> 8;

  const int lane = t & 63;
  const int wv   = t >> 6;
  const int wm   = wv >> 1, wn = wv & 1;
  const int lrow = lane & 15;
  const int lk8  = (lane >> 4) * 8;

  const char* Ab = (const char*)(Q + ((size_t)b * Tn + qt * BM) * Cn);
  const char* Bb = (const char*)(K + ((size_t)b * Tn + kt * BN) * Cn);

  f32x4 acc[4][4] = {};

  for (int k0 = 0; k0 < Cn; k0 += BKK) {
    stage_tile(Ab + (size_t)k0 * 2, As, t);
    stage_tile(Bb + (size_t)k0 * 2, Bs, t);
    __syncthreads();
#pragma unroll
    for (int ks = 0; ks < 2; ++ks) {
      bf16x8 a[4], bfr[4];
#pragma unroll
      for (int mi = 0; mi < 4; ++mi)
        a[mi] = *(const bf16x8*)&As[(wm * 64 + mi * 16 + lrow) * BKK + ks * 32 + lk8];
#pragma unroll
      for (int ni = 0; ni < 4; ++ni)
        bfr[ni] = *(const bf16x8*)&Bs[(wn * 64 + ni * 16 + lrow) * BKK + ks * 32 + lk8];
#pragma unroll
      for (int mi = 0; mi < 4; ++mi)
#pragma unroll
        for (int ni = 0; ni < 4; ++ni)
          acc[mi][ni] = __builtin_amdgcn_mfma_f32_16x16x32_bf16(a[mi], bfr[ni], acc[mi][ni], 0, 0, 0);
    }
    __syncthreads();
  }

  const float scale = 0.036084391824351615f;  // 1/sqrt(768)
  float csum[4] = {0.f, 0.f, 0.f, 0.f};
#pragma unroll
  for (int ni = 0; ni < 4; ++ni)
#pragma unroll
    for (int mi = 0; mi < 4; ++mi)
#pragma unroll
      for (int r = 0; r < 4; ++r) {
        float s = acc[mi][ni][r] * scale;
        csum[ni] += 1.f / (1.f + __expf(-s));
      }
#pragma unroll
  for (int ni = 0; ni < 4; ++ni) {
    csum[ni] += __shfl_xor(csum[ni], 16);
    csum[ni] += __shfl_xor(csum[ni], 32);
  }
  if (lane < 16) {
#pragma unroll
    for (int ni = 0; ni < 4; ++ni)
      atomicAdd(&wsum[(size_t)b * Tn + kt * BN + wn * 64 + ni * 16 + lane], csum[ni]);
  }
}

// ---------------- y[b,c] = sum_k w[b,k] * x[b,k,c]  (fp32 x, fp32 accum)
__global__ __launch_bounds__(192)
void wx_kernel(const float* __restrict__ w, const float* __restrict__ x,
               float* __restrict__ y)
{
  const int b = blockIdx.x, ks = blockIdx.y;   // grid (16, 32): 64 k's per block
  const int t = threadIdx.x;                   // 192 threads -> 192 float4 = 768 floats
  const float*  wr = w + (size_t)b * Tn + ks * 64;
  const float4v* xr = (const float4v*)(x + ((size_t)b * Tn + (size_t)ks * 64) * Cn);
  float4v acc = {};
#pragma unroll 4
  for (int k = 0; k < 64; ++k) {
    const float wk = wr[k];
    const float4v xv = xr[(size_t)k * 192 + t];
#pragma unroll
    for (int j = 0; j < 4; ++j) acc[j] += wk * xv[j];
  }
  float* yb = y + (size_t)b * Cn + t * 4;
#pragma unroll
  for (int j = 0; j < 4; ++j) atomicAdd(yb + j, acc[j]);
}

// ---------------- out_pre[b,d] = ( y[b,:].Wv[d,:] + sw[b]*bv[d] ) / T
__global__ __launch_bounds__(256)
void vproj_kernel(const float* __restrict__ y, const float* __restrict__ wsum,
                  const float* __restrict__ Wv, const float* __restrict__ bv,
                  float* __restrict__ opre)
{
  __shared__ float ys[Cn];
  __shared__ float red[4];
  const int b = blockIdx.x, t = threadIdx.x;
  float s = 0.f;
  for (int i = t; i < Tn; i += 256) s += wsum[(size_t)b * Tn + i];
#pragma unroll
  for (int off = 32; off; off >>= 1) s += __shfl_down(s, off);
  if ((t & 63) == 0) red[t >> 6] = s;
  for (int i = t; i < Cn; i += 256) ys[i] = y[(size_t)b * Cn + i];
  __syncthreads();
  const float sw = red[0] + red[1] + red[2] + red[3];
  const float4v* ysv = (const float4v*)ys;
#pragma unroll
  for (int dd = 0; dd < 3; ++dd) {
    const int d = t + dd * 256;
    const float4v* wrow = (const float4v*)(Wv + (size_t)d * Cn);
    float4v a = {};
    for (int c = 0; c < Cn / 4; ++c) {
      const float4v wv4 = wrow[c];
      const float4v yv4 = ysv[c];
#pragma unroll
      for (int j = 0; j < 4; ++j) a[j] += wv4[j] * yv4[j];
    }
    const float dot = a[0] + a[1] + a[2] + a[3];
    opre[(size_t)b * Cn + d] = (dot + sw * bv[d]) * (1.f / 2048.f);
  }
}

// ---------------- BatchNorm1d over batch dim (training stats, biased var)
__global__ void bn_kernel(const float* __restrict__ out_pre,
                          const float* __restrict__ gamma, const float* __restrict__ beta,
                          float* __restrict__ out)
{
  const int d = blockIdx.x * 256 + threadIdx.x;  // 768 columns
  float vals[16];
  float s = 0.f;
#pragma unroll
  for (int b = 0; b < 16; ++b) { vals[b] = out_pre[b * Cn + d]; s += vals[b]; }
  const float mu = s * (1.f / 16.f);
  float s2 = 0.f;
#pragma unroll
  for (int b = 0; b < 16; ++b) { float t2 = vals[b] - mu; s2 += t2 * t2; }
  const float inv = rsqrtf(s2 * (1.f / 16.f) + 1e-5f);
  const float g = gamma[d] * inv, be = beta[d];
#pragma unroll
  for (int b = 0; b < 16; ++b) out[b * Cn + d] = (vals[b] - mu) * g + be;
}

// ---------------- conversions
__global__ void cvt_x_kernel(const float* __restrict__ x, __hip_bfloat16* __restrict__ xb, int n4)
{
  int i = blockIdx.x * blockDim.x + threadIdx.x;
  if (i >= n4) return;
  float4v v = ((const float4v*)x)[i];
  short4v o;
#pragma unroll
  for (int j = 0; j < 4; ++j) o[j] = __builtin_bit_cast(short, __float2bfloat16(v[j]));
  ((short4v*)xb)[i] = o;
}

__global__ void cvt_w_kernel(const float* __restrict__ Wq, const float* __restrict__ Wk,
                             const float* __restrict__ bq, const float* __restrict__ bk,
                             __hip_bfloat16* __restrict__ Wc, float* __restrict__ biasc)
{
  int idx = blockIdx.x * 256 + threadIdx.x;
  if (idx >= NQK * Cn) return;
  int n = idx / Cn, c = idx - n * Cn;
  const float* W;
  const float* bb;
  int nn;
  if (n < Cn) { W = Wq; bb = bq; nn = n; }
  else        { W = Wk; bb = bk; nn = n - Cn; }
  Wc[idx] = __float2bfloat16(W[(size_t)nn * Cn + c]);
  if (c == 0) biasc[n] = bb[nn];
}

extern "C" void kernel_launch(void* const* d_in, const int* in_sizes, int n_in,
                              void* d_out, int out_size, void* d_ws, size_t ws_size,
                              hipStream_t stream)
{
  const float* x  = (const float*)d_in[0];
  const float* Wq = (const float*)d_in[1];
  const float* bq = (const float*)d_in[2];
  const float* Wk = (const float*)d_in[3];
  const float* bk = (const float*)d_in[4];
  const float* Wv = (const float*)d_in[5];
  const float* bv = (const float*)d_in[6];
  const float* gamma = (const float*)d_in[7];
  const float* beta  = (const float*)d_in[8];
  float* out = (float*)d_out;

  char* ws = (char*)d_ws;
  // workspace layout (~146.5 MiB)
  __hip_bfloat16* xb  = (__hip_bfloat16*)(ws);                  // 32768*768*2 = 50,331,648
  __hip_bfloat16* Wc  = (__hip_bfloat16*)(ws + 50331648);       // 1536*768*2  =  2,359,296
  float*          bc  = (float*)         (ws + 52690944);       // 1536*4      =      6,144
  __hip_bfloat16* Qb  = (__hip_bfloat16*)(ws + 52697088);       // 50,331,648
  __hip_bfloat16* Kb  = (__hip_bfloat16*)(ws + 103028736);      // 50,331,648
  float*          wsum= (float*)         (ws + 153360384);      // 16*2048*4   =    131,072
  float*          yv  = (float*)         (ws + 153491456);      // 16*768*4    =     49,152
  float*          opre= (float*)         (ws + 153540608);      // 16*768*4    =     49,152

  (void)in_sizes; (void)n_in; (void)out_size; (void)ws_size;

  hipMemsetAsync(wsum, 0, 131072 + 49152, stream);  // wsum + y (contiguous)

  cvt_x_kernel<<<dim3(24576), 256, 0, stream>>>(x, xb, 25165824 / 4);
  cvt_w_kernel<<<dim3((NQK * Cn) / 256), 256, 0, stream>>>(Wq, Wk, bq, bk, Wc, bc);

  proj_kernel<<<dim3(NQK / BN, (Bn * Tn) / BM), 256, 0, stream>>>(
      (const __bf16*)xb, (const __bf16*)Wc, bc, Qb, Kb);

  attn_kernel<<<dim3(Tn / BN, Tn / BM, Bn), 256, 0, stream>>>(
      (const __bf16*)Qb, (const __bf16*)Kb, wsum);

  wx_kernel<<<dim3(Bn, 32), 192, 0, stream>>>(wsum, x, yv);

  vproj_kernel<<<dim3(Bn), 256, 0, stream>>>(yv, wsum, Wv, bv, opre);

  bn_kernel<<<dim3(3), 256, 0, stream>>>(opre, gamma, beta, out);
}

// Round 3
// 352.385 us; speedup vs baseline: 1.0017x; 1.0017x over previous
//
#include <hip/hip_runtime.h>
#include <hip/hip_bf16.h>

typedef __bf16 bf16x8 __attribute__((ext_vector_type(8)));
typedef float  f32x4  __attribute__((ext_vector_type(4)));
typedef float  float4v __attribute__((ext_vector_type(4)));
typedef short  short4v __attribute__((ext_vector_type(4)));

static constexpr int Tn  = 2048;
static constexpr int Bn  = 16;
static constexpr int Cn  = 768;
static constexpr int NQK = 2 * Cn;   // 1536
static constexpr int KT  = 12;       // 768 / 64 K-steps

#define MFMA16x16(a, b, c) __builtin_amdgcn_mfma_f32_16x16x32_bf16(a, b, c, 0, 0, 0)

__device__ __forceinline__ void gload_lds16(const void* g, void* l) {
  __builtin_amdgcn_global_load_lds((const __attribute__((address_space(1))) void*)g,
                                   (__attribute__((address_space(3))) void*)l, 16, 0, 0);
}

// Stage one 16KB unit: [256 rows][32 bf16 = 64B] of a ks-half, global row stride 1536B.
// LDS dest linear (tid*16 + chunk*8192); global source pre-inverse-swizzled:
//   swz(o) = o ^ (((o>>7)&3)<<4)   (involution, preserves 16B chunks)
__device__ __forceinline__ void stage_unit(const char* gk, char* ldsu, int tid) {
#pragma unroll
  for (int c = 0; c < 2; ++c) {
    const int o   = tid * 16 + c * 8192;
    const int row = o >> 6;
    const int col = (o & 63) ^ (((o >> 7) & 3) << 4);
    gload_lds16(gk + (size_t)row * 1536 + col, ldsu + o);
  }
}

// fragment read with matching swizzle: unit row r (0..255), lane col-bytes lcb
__device__ __forceinline__ bf16x8 frag_ld(const char* unit, int r, int lcb) {
  return *(const bf16x8*)(unit + r * 64 + (lcb ^ (((r >> 1) & 3) << 4)));
}

#define DS_WAIT do { asm volatile("s_waitcnt lgkmcnt(0)" ::: "memory"); \
                     __builtin_amdgcn_sched_barrier(0); } while (0)

// ---- 8-phase-style 256x256 K-loop core. Ab/Bb: byte bases of the 256-row panels
// (row stride 1536B). acc[8][4]: wave's 128x64 output (8 m-frags x 4 n-frags).
__device__ __forceinline__ void gemm_core(const char* Ab, const char* Bb, char* lds,
                                          int tid, f32x4 (&acc)[8][4]) {
  const int lane = tid & 63;
  const int w    = tid >> 6;
  const int wm   = w >> 2;        // 0..1
  const int wn   = w & 3;         // 0..3
  const int lrow = lane & 15;
  const int lcb  = (lane >> 4) * 16;
  const int ar   = wm * 128 + lrow;   // + mh*64 + mi*16
  const int br   = wn * 64 + lrow;    // + ni*16

  // prologue: stage tile 0 (all 4 units), one-time drain
  stage_unit(Ab,      lds + 0,     tid);
  stage_unit(Bb,      lds + 32768, tid);
  stage_unit(Ab + 64, lds + 16384, tid);
  stage_unit(Bb + 64, lds + 49152, tid);
  asm volatile("s_waitcnt vmcnt(0)" ::: "memory");
  __builtin_amdgcn_s_barrier();

  for (int t = 0; t < KT; ++t) {
    const char* bp  = lds + (t & 1) * 65536;
    char*       bq  = lds + ((t + 1) & 1) * 65536;
    const char* gAn = Ab + (size_t)(t + 1) * 128;
    const char* gBn = Bb + (size_t)(t + 1) * 128;
    const bool  st  = (t < KT - 1);
    bf16x8 aF[4], bF[4];

    // ---- phase 0: ks=0, mh=0 (read B ks0 + A ks0 low; stage Ak0(t+1))
#pragma unroll
    for (int i = 0; i < 4; ++i) bF[i] = frag_ld(bp + 32768, br + i * 16, lcb);
#pragma unroll
    for (int i = 0; i < 4; ++i) aF[i] = frag_ld(bp, ar + i * 16, lcb);
    if (st) stage_unit(gAn, bq, tid);
    __builtin_amdgcn_s_barrier();
    DS_WAIT;
    __builtin_amdgcn_s_setprio(1);
#pragma unroll
    for (int i = 0; i < 4; ++i)
#pragma unroll
      for (int j = 0; j < 4; ++j)
        acc[i][j] = MFMA16x16(aF[i], bF[j], acc[i][j]);
    __builtin_amdgcn_s_setprio(0);
    __builtin_amdgcn_s_barrier();

    // ---- phase 1: ks=0, mh=1 (stage Bk0(t+1); counted vmcnt covers this tile's ks1)
#pragma unroll
    for (int i = 0; i < 4; ++i) aF[i] = frag_ld(bp, ar + 64 + i * 16, lcb);
    if (st) { stage_unit(gBn, bq + 32768, tid);
              asm volatile("s_waitcnt vmcnt(4)" ::: "memory"); }
    else    { asm volatile("s_waitcnt vmcnt(0)" ::: "memory"); }
    __builtin_amdgcn_s_barrier();
    DS_WAIT;
    __builtin_amdgcn_s_setprio(1);
#pragma unroll
    for (int i = 0; i < 4; ++i)
#pragma unroll
      for (int j = 0; j < 4; ++j)
        acc[4 + i][j] = MFMA16x16(aF[i], bF[j], acc[4 + i][j]);
    __builtin_amdgcn_s_setprio(0);
    __builtin_amdgcn_s_barrier();

    // ---- phase 2: ks=1, mh=0 (read B ks1 + A ks1 low; stage Ak1(t+1))
#pragma unroll
    for (int i = 0; i < 4; ++i) bF[i] = frag_ld(bp + 49152, br + i * 16, lcb);
#pragma unroll
    for (int i = 0; i < 4; ++i) aF[i] = frag_ld(bp + 16384, ar + i * 16, lcb);
    if (st) stage_unit(gAn + 64, bq + 16384, tid);
    __builtin_amdgcn_s_barrier();
    DS_WAIT;
    __builtin_amdgcn_s_setprio(1);
#pragma unroll
    for (int i = 0; i < 4; ++i)
#pragma unroll
      for (int j = 0; j < 4; ++j)
        acc[i][j] = MFMA16x16(aF[i], bF[j], acc[i][j]);
    __builtin_amdgcn_s_setprio(0);
    __builtin_amdgcn_s_barrier();

    // ---- phase 3: ks=1, mh=1 (stage Bk1(t+1); counted vmcnt covers next tile's ks0)
#pragma unroll
    for (int i = 0; i < 4; ++i) aF[i] = frag_ld(bp + 16384, ar + 64 + i * 16, lcb);
    if (st) { stage_unit(gBn + 64, bq + 49152, tid);
              asm volatile("s_waitcnt vmcnt(4)" ::: "memory"); }
    else    { asm volatile("s_waitcnt vmcnt(0)" ::: "memory"); }
    __builtin_amdgcn_s_barrier();
    DS_WAIT;
    __builtin_amdgcn_s_setprio(1);
#pragma unroll
    for (int i = 0; i < 4; ++i)
#pragma unroll
      for (int j = 0; j < 4; ++j)
        acc[4 + i][j] = MFMA16x16(aF[i], bF[j], acc[4 + i][j]);
    __builtin_amdgcn_s_setprio(0);
    __builtin_amdgcn_s_barrier();
  }
}

// ---------------- fused QK projection (256x256 tiles, coalesced banded epilogue)
__global__ __launch_bounds__(512, 2)
void proj_kernel(const __bf16* __restrict__ X, const __bf16* __restrict__ W,
                 const float* __restrict__ bias,
                 __hip_bfloat16* __restrict__ Qo, __hip_bfloat16* __restrict__ Ko)
{
  __shared__ char lds[131072];
  int f = blockIdx.x;                 // nwg = 128*6 = 768 (divisible by 8)
  f = (f & 7) * 96 + (f >> 3);        // XCD-chunked (bijective)
  const int tn = f % 6, tm = f / 6;
  const int tile_n = tn * 256, tile_m = tm * 256;

  const int tid  = threadIdx.x;
  const int lane = tid & 63;
  const int w    = tid >> 6;
  const int wm   = w >> 2, wn = w & 3;
  const int lrow = lane & 15;
  const int crow = (lane >> 4) * 4;

  const char* Ab = (const char*)(X + (size_t)tile_m * Cn);
  const char* Bb = (const char*)(W + (size_t)tile_n * Cn);

  f32x4 acc[8][4] = {};
  gemm_core(Ab, Bb, lds, tid, acc);

  // bias per n-col (4 frags)
  float bias4[4];
#pragma unroll
  for (int ni = 0; ni < 4; ++ni) bias4[ni] = bias[tile_n + wn * 64 + ni * 16 + lrow];

  char* outbase = (char*)(tn < 3 ? Qo : Ko);
  const size_t nbyte = (size_t)(tn < 3 ? tile_n : tile_n - Cn) * 2;

  // 4 bands of 64 rows; LDS repack [64][264 bf16] -> coalesced 16B stores
  __bf16* cb = (__bf16*)lds;
  for (int rb = 0; rb < 4; ++rb) {
    __syncthreads();
    if (wm == (rb >> 1)) {
#pragma unroll
      for (int mi2 = 0; mi2 < 4; ++mi2) {
        const int mi = (rb & 1) * 4 + mi2;
        const int lr = mi2 * 16 + crow;
#pragma unroll
        for (int ni = 0; ni < 4; ++ni) {
          const int col = wn * 64 + ni * 16 + lrow;
#pragma unroll
          for (int r = 0; r < 4; ++r)
            cb[(lr + r) * 264 + col] = (__bf16)(acc[mi][ni][r] + bias4[ni]);
        }
      }
    }
    __syncthreads();
    const int row   = tid >> 3;
    const int cbyte = (tid & 7) * 64;
    char* gout = outbase + (size_t)(tile_m + rb * 64 + row) * 1536 + nbyte + cbyte;
    const char* lsrc = (const char*)cb + row * 528 + cbyte;
#pragma unroll
    for (int i = 0; i < 4; ++i)
      *(float4v*)(gout + i * 16) = *(const float4v*)(lsrc + i * 16);
  }
}

// ---------------- attention colsum: w[b,k'] += sum_q sigmoid(scale * Q_q . K_k')
__global__ __launch_bounds__(512, 2)
void attn_kernel(const __bf16* __restrict__ Q, const __bf16* __restrict__ K,
                 float* __restrict__ wsum)
{
  __shared__ char lds[131072];
  int f = blockIdx.x;                 // nwg = 8*8*16 = 1024
  f = (f & 7) * 128 + (f >> 3);       // XCD-chunked: ~2 batches per XCD
  const int kt = f & 7, qt = (f >> 3) & 7, b = f >> 6;

  const int tid  = threadIdx.x;
  const int lane = tid & 63;
  const int wn   = (tid >> 6) & 3;

  const char* Ab = (const char*)(Q + ((size_t)b * Tn + qt * 256) * Cn);
  const char* Bb = (const char*)(K + ((size_t)b * Tn + kt * 256) * Cn);

  f32x4 acc[8][4] = {};
  gemm_core(Ab, Bb, lds, tid, acc);

  const float scale = 0.036084391824351615f;  // 1/sqrt(768)
  float csum[4] = {0.f, 0.f, 0.f, 0.f};
#pragma unroll
  for (int mi = 0; mi < 8; ++mi)
#pragma unroll
    for (int ni = 0; ni < 4; ++ni)
#pragma unroll
      for (int r = 0; r < 4; ++r) {
        const float s = acc[mi][ni][r] * scale;
        csum[ni] += 1.f / (1.f + __expf(-s));
      }
#pragma unroll
  for (int ni = 0; ni < 4; ++ni) {
    csum[ni] += __shfl_xor(csum[ni], 16);
    csum[ni] += __shfl_xor(csum[ni], 32);
  }
  if (lane < 16) {
#pragma unroll
    for (int ni = 0; ni < 4; ++ni)
      atomicAdd(&wsum[(size_t)b * Tn + kt * 256 + wn * 64 + ni * 16 + lane], csum[ni]);
  }
}

// ---------------- y[b,c] = sum_k w[b,k] * x[b,k,c]  (fp32 x, fp32 accum)
__global__ __launch_bounds__(192)
void wx_kernel(const float* __restrict__ w, const float* __restrict__ x,
               float* __restrict__ y)
{
  const int b = blockIdx.x, ks = blockIdx.y;   // grid (16, 32): 64 k's per block
  const int t = threadIdx.x;                   // 192 threads -> 768 floats
  const float*  wr = w + (size_t)b * Tn + ks * 64;
  const float4v* xr = (const float4v*)(x + ((size_t)b * Tn + (size_t)ks * 64) * Cn);
  float4v acc = {};
#pragma unroll 4
  for (int k = 0; k < 64; ++k) {
    const float wk = wr[k];
    const float4v xv = xr[(size_t)k * 192 + t];
#pragma unroll
    for (int j = 0; j < 4; ++j) acc[j] += wk * xv[j];
  }
  float* yb = y + (size_t)b * Cn + t * 4;
#pragma unroll
  for (int j = 0; j < 4; ++j) atomicAdd(yb + j, acc[j]);
}

// ---------------- out_pre[b,d] = ( y[b,:].Wv[d,:] + sw[b]*bv[d] ) / T
__global__ __launch_bounds__(256)
void vproj_kernel(const float* __restrict__ y, const float* __restrict__ wsum,
                  const float* __restrict__ Wv, const float* __restrict__ bv,
                  float* __restrict__ opre)
{
  __shared__ float ys[Cn];
  __shared__ float red[4];
  const int b = blockIdx.x, t = threadIdx.x;
  float s = 0.f;
  for (int i = t; i < Tn; i += 256) s += wsum[(size_t)b * Tn + i];
#pragma unroll
  for (int off = 32; off; off >>= 1) s += __shfl_down(s, off);
  if ((t & 63) == 0) red[t >> 6] = s;
  for (int i = t; i < Cn; i += 256) ys[i] = y[(size_t)b * Cn + i];
  __syncthreads();
  const float sw = red[0] + red[1] + red[2] + red[3];
  const float4v* ysv = (const float4v*)ys;
#pragma unroll
  for (int dd = 0; dd < 3; ++dd) {
    const int d = t + dd * 256;
    const float4v* wrow = (const float4v*)(Wv + (size_t)d * Cn);
    float4v a = {};
    for (int c = 0; c < Cn / 4; ++c) {
      const float4v wv4 = wrow[c];
      const float4v yv4 = ysv[c];
#pragma unroll
      for (int j = 0; j < 4; ++j) a[j] += wv4[j] * yv4[j];
    }
    const float dot = a[0] + a[1] + a[2] + a[3];
    opre[(size_t)b * Cn + d] = (dot + sw * bv[d]) * (1.f / 2048.f);
  }
}

// ---------------- BatchNorm1d over batch dim (training stats, biased var)
__global__ void bn_kernel(const float* __restrict__ out_pre,
                          const float* __restrict__ gamma, const float* __restrict__ beta,
                          float* __restrict__ out)
{
  const int d = blockIdx.x * 256 + threadIdx.x;  // 768 columns
  float vals[16];
  float s = 0.f;
#pragma unroll
  for (int b = 0; b < 16; ++b) { vals[b] = out_pre[b * Cn + d]; s += vals[b]; }
  const float mu = s * (1.f / 16.f);
  float s2 = 0.f;
#pragma unroll
  for (int b = 0; b < 16; ++b) { float t2 = vals[b] - mu; s2 += t2 * t2; }
  const float inv = rsqrtf(s2 * (1.f / 16.f) + 1e-5f);
  const float g = gamma[d] * inv, be = beta[d];
#pragma unroll
  for (int b = 0; b < 16; ++b) out[b * Cn + d] = (vals[b] - mu) * g + be;
}

// ---------------- conversions
__global__ void cvt_x_kernel(const float* __restrict__ x, __hip_bfloat16* __restrict__ xb, int n4)
{
  int i = blockIdx.x * blockDim.x + threadIdx.x;
  if (i >= n4) return;
  float4v v = ((const float4v*)x)[i];
  short4v o;
#pragma unroll
  for (int j = 0; j < 4; ++j) o[j] = __builtin_bit_cast(short, __float2bfloat16(v[j]));
  ((short4v*)xb)[i] = o;
}

__global__ void cvt_w_kernel(const float* __restrict__ Wq, const float* __restrict__ Wk,
                             const float* __restrict__ bq, const float* __restrict__ bk,
                             __hip_bfloat16* __restrict__ Wc, float* __restrict__ biasc)
{
  int idx = blockIdx.x * 256 + threadIdx.x;
  if (idx >= NQK * Cn) return;
  int n = idx / Cn, c = idx - n * Cn;
  const float* W;
  const float* bb;
  int nn;
  if (n < Cn) { W = Wq; bb = bq; nn = n; }
  else        { W = Wk; bb = bk; nn = n - Cn; }
  Wc[idx] = __float2bfloat16(W[(size_t)nn * Cn + c]);
  if (c == 0) biasc[n] = bb[nn];
}

extern "C" void kernel_launch(void* const* d_in, const int* in_sizes, int n_in,
                              void* d_out, int out_size, void* d_ws, size_t ws_size,
                              hipStream_t stream)
{
  const float* x  = (const float*)d_in[0];
  const float* Wq = (const float*)d_in[1];
  const float* bq = (const float*)d_in[2];
  const float* Wk = (const float*)d_in[3];
  const float* bk = (const float*)d_in[4];
  const float* Wv = (const float*)d_in[5];
  const float* bv = (const float*)d_in[6];
  const float* gamma = (const float*)d_in[7];
  const float* beta  = (const float*)d_in[8];
  float* out = (float*)d_out;

  char* ws = (char*)d_ws;
  // workspace layout (~146.5 MiB)
  __hip_bfloat16* xb  = (__hip_bfloat16*)(ws);                  // 32768*768*2 = 50,331,648
  __hip_bfloat16* Wc  = (__hip_bfloat16*)(ws + 50331648);       // 1536*768*2  =  2,359,296
  float*          bc  = (float*)         (ws + 52690944);       // 1536*4      =      6,144
  __hip_bfloat16* Qb  = (__hip_bfloat16*)(ws + 52697088);       // 50,331,648
  __hip_bfloat16* Kb  = (__hip_bfloat16*)(ws + 103028736);      // 50,331,648
  float*          wsum= (float*)         (ws + 153360384);      // 16*2048*4   =    131,072
  float*          yv  = (float*)         (ws + 153491456);      // 16*768*4    =     49,152
  float*          opre= (float*)         (ws + 153540608);      // 16*768*4    =     49,152

  (void)in_sizes; (void)n_in; (void)out_size; (void)ws_size;

  hipMemsetAsync(wsum, 0, 131072 + 49152, stream);  // wsum + y (contiguous)

  cvt_x_kernel<<<dim3(24576), 256, 0, stream>>>(x, xb, 25165824 / 4);
  cvt_w_kernel<<<dim3((NQK * Cn) / 256), 256, 0, stream>>>(Wq, Wk, bq, bk, Wc, bc);

  proj_kernel<<<dim3(768), 512, 0, stream>>>(
      (const __bf16*)xb, (const __bf16*)Wc, bc, Qb, Kb);

  attn_kernel<<<dim3(1024), 512, 0, stream>>>(
      (const __bf16*)Qb, (const __bf16*)Kb, wsum);

  wx_kernel<<<dim3(Bn, 32), 192, 0, stream>>>(wsum, x, yv);

  vproj_kernel<<<dim3(Bn), 256, 0, stream>>>(yv, wsum, Wv, bv, opre);

  bn_kernel<<<dim3(3), 256, 0, stream>>>(opre, gamma, beta, out);
}

// Round 4
// 319.327 us; speedup vs baseline: 1.1054x; 1.1035x over previous
//
#include <hip/hip_runtime.h>
#include <hip/hip_bf16.h>

typedef __bf16 bf16x8 __attribute__((ext_vector_type(8)));
typedef float  f32x4  __attribute__((ext_vector_type(4)));
typedef float  float4v __attribute__((ext_vector_type(4)));
typedef short  short4v __attribute__((ext_vector_type(4)));

static constexpr int Tn  = 2048;
static constexpr int Bn  = 16;
static constexpr int Cn  = 768;
static constexpr int KT  = 12;       // 768 / 64 K-steps

#define MFMA16x16(a, b, c) __builtin_amdgcn_mfma_f32_16x16x32_bf16(a, b, c, 0, 0, 0)

__device__ __forceinline__ void gload_lds16(const void* g, void* l) {
  __builtin_amdgcn_global_load_lds((const __attribute__((address_space(1))) void*)g,
                                   (__attribute__((address_space(3))) void*)l, 16, 0, 0);
}

// ---------- 256x256 8-phase core (round-3, verified) ----------
// Stage one 16KB unit: [256 rows][32 bf16 = 64B] of a ks-half, global row stride 1536B.
__device__ __forceinline__ void stage_unit(const char* gk, char* ldsu, int tid) {
#pragma unroll
  for (int c = 0; c < 2; ++c) {
    const int o   = tid * 16 + c * 8192;
    const int row = o >> 6;
    const int col = (o & 63) ^ (((o >> 7) & 3) << 4);
    gload_lds16(gk + (size_t)row * 1536 + col, ldsu + o);
  }
}

__device__ __forceinline__ bf16x8 frag_ld(const char* unit, int r, int lcb) {
  return *(const bf16x8*)(unit + r * 64 + (lcb ^ (((r >> 1) & 3) << 4)));
}

#define DS_WAIT do { asm volatile("s_waitcnt lgkmcnt(0)" ::: "memory"); \
                     __builtin_amdgcn_sched_barrier(0); } while (0)

__device__ __forceinline__ void gemm_core(const char* Ab, const char* Bb, char* lds,
                                          int tid, f32x4 (&acc)[8][4]) {
  const int lane = tid & 63;
  const int w    = tid >> 6;
  const int wm   = w >> 2;
  const int wn   = w & 3;
  const int lrow = lane & 15;
  const int lcb  = (lane >> 4) * 16;
  const int ar   = wm * 128 + lrow;
  const int br   = wn * 64 + lrow;

  stage_unit(Ab,      lds + 0,     tid);
  stage_unit(Bb,      lds + 32768, tid);
  stage_unit(Ab + 64, lds + 16384, tid);
  stage_unit(Bb + 64, lds + 49152, tid);
  asm volatile("s_waitcnt vmcnt(0)" ::: "memory");
  __builtin_amdgcn_s_barrier();

  for (int t = 0; t < KT; ++t) {
    const char* bp  = lds + (t & 1) * 65536;
    char*       bq  = lds + ((t + 1) & 1) * 65536;
    const char* gAn = Ab + (size_t)(t + 1) * 128;
    const char* gBn = Bb + (size_t)(t + 1) * 128;
    const bool  st  = (t < KT - 1);
    bf16x8 aF[4], bF[4];

    // phase 0
#pragma unroll
    for (int i = 0; i < 4; ++i) bF[i] = frag_ld(bp + 32768, br + i * 16, lcb);
#pragma unroll
    for (int i = 0; i < 4; ++i) aF[i] = frag_ld(bp, ar + i * 16, lcb);
    if (st) stage_unit(gAn, bq, tid);
    __builtin_amdgcn_s_barrier();
    DS_WAIT;
    __builtin_amdgcn_s_setprio(1);
#pragma unroll
    for (int i = 0; i < 4; ++i)
#pragma unroll
      for (int j = 0; j < 4; ++j)
        acc[i][j] = MFMA16x16(aF[i], bF[j], acc[i][j]);
    __builtin_amdgcn_s_setprio(0);
    __builtin_amdgcn_s_barrier();

    // phase 1
#pragma unroll
    for (int i = 0; i < 4; ++i) aF[i] = frag_ld(bp, ar + 64 + i * 16, lcb);
    if (st) { stage_unit(gBn, bq + 32768, tid);
              asm volatile("s_waitcnt vmcnt(4)" ::: "memory"); }
    else    { asm volatile("s_waitcnt vmcnt(0)" ::: "memory"); }
    __builtin_amdgcn_s_barrier();
    DS_WAIT;
    __builtin_amdgcn_s_setprio(1);
#pragma unroll
    for (int i = 0; i < 4; ++i)
#pragma unroll
      for (int j = 0; j < 4; ++j)
        acc[4 + i][j] = MFMA16x16(aF[i], bF[j], acc[4 + i][j]);
    __builtin_amdgcn_s_setprio(0);
    __builtin_amdgcn_s_barrier();

    // phase 2
#pragma unroll
    for (int i = 0; i < 4; ++i) bF[i] = frag_ld(bp + 49152, br + i * 16, lcb);
#pragma unroll
    for (int i = 0; i < 4; ++i) aF[i] = frag_ld(bp + 16384, ar + i * 16, lcb);
    if (st) stage_unit(gAn + 64, bq + 16384, tid);
    __builtin_amdgcn_s_barrier();
    DS_WAIT;
    __builtin_amdgcn_s_setprio(1);
#pragma unroll
    for (int i = 0; i < 4; ++i)
#pragma unroll
      for (int j = 0; j < 4; ++j)
        acc[i][j] = MFMA16x16(aF[i], bF[j], acc[i][j]);
    __builtin_amdgcn_s_setprio(0);
    __builtin_amdgcn_s_barrier();

    // phase 3
#pragma unroll
    for (int i = 0; i < 4; ++i) aF[i] = frag_ld(bp + 16384, ar + 64 + i * 16, lcb);
    if (st) { stage_unit(gBn + 64, bq + 49152, tid);
              asm volatile("s_waitcnt vmcnt(4)" ::: "memory"); }
    else    { asm volatile("s_waitcnt vmcnt(0)" ::: "memory"); }
    __builtin_amdgcn_s_barrier();
    DS_WAIT;
    __builtin_amdgcn_s_setprio(1);
#pragma unroll
    for (int i = 0; i < 4; ++i)
#pragma unroll
      for (int j = 0; j < 4; ++j)
        acc[4 + i][j] = MFMA16x16(aF[i], bF[j], acc[4 + i][j]);
    __builtin_amdgcn_s_setprio(0);
    __builtin_amdgcn_s_barrier();
  }
}

// ---------------- Z = X * Gt^T  (M=32768, N=768, K=768), bf16 out, no bias
__global__ __launch_bounds__(512, 2)
void z_kernel(const __bf16* __restrict__ X, const __bf16* __restrict__ Gt,
              __hip_bfloat16* __restrict__ Zo)
{
  __shared__ char lds[131072];
  int f = blockIdx.x;                 // nwg = 128*3 = 384
  f = (f & 7) * 48 + (f >> 3);        // XCD-chunked; tn fastest within XCD -> X reused 3x in L2
  const int tn = f % 3, tm = f / 3;
  const int tile_n = tn * 256, tile_m = tm * 256;

  const int tid  = threadIdx.x;
  const int lane = tid & 63;
  const int w    = tid >> 6;
  const int wm   = w >> 2, wn = w & 3;
  const int lrow = lane & 15;
  const int crow = (lane >> 4) * 4;

  const char* Ab = (const char*)(X + (size_t)tile_m * Cn);
  const char* Bb = (const char*)(Gt + (size_t)tile_n * Cn);

  f32x4 acc[8][4] = {};
  gemm_core(Ab, Bb, lds, tid, acc);

  char* outbase = (char*)Zo;
  __bf16* cb = (__bf16*)lds;
  for (int rb = 0; rb < 4; ++rb) {
    __syncthreads();
    if (wm == (rb >> 1)) {
#pragma unroll
      for (int mi2 = 0; mi2 < 4; ++mi2) {
        const int mi = (rb & 1) * 4 + mi2;
        const int lr = mi2 * 16 + crow;
#pragma unroll
        for (int ni = 0; ni < 4; ++ni) {
          const int col = wn * 64 + ni * 16 + lrow;
#pragma unroll
          for (int r = 0; r < 4; ++r)
            cb[(lr + r) * 264 + col] = (__bf16)acc[mi][ni][r];
        }
      }
    }
    __syncthreads();
    const int row   = tid >> 3;
    const int cbyte = (tid & 7) * 64;
    char* gout = outbase + (size_t)(tile_m + rb * 64 + row) * 1536 + (size_t)tile_n * 2 + cbyte;
    const char* lsrc = (const char*)cb + row * 528 + cbyte;
#pragma unroll
    for (int i = 0; i < 4; ++i)
      *(float4v*)(gout + i * 16) = *(const float4v*)(lsrc + i * 16);
  }
}

// ---------------- attention colsum: wsum[b,k] += sum_q sigmoid(scale*(Z_q.X_k + u_q + v_k))
__global__ __launch_bounds__(512, 2)
void attn_kernel(const __bf16* __restrict__ Z, const __bf16* __restrict__ X,
                 const float* __restrict__ u, const float* __restrict__ v,
                 float* __restrict__ wsum)
{
  __shared__ char lds[131072];
  const int orig = blockIdx.x;        // 1024
  const int xcd = orig & 7, l = orig >> 3;
  const int b   = xcd * 2 + (l >> 6);
  const int r_  = l & 63;
  const int sub = r_ >> 4, qq = (r_ >> 2) & 3, kk = r_ & 3;
  const int sq  = sub >> 1, sk = (sub & 1) ^ (sq & 1);   // snake over 4x4 sub-squares
  const int qt  = sq * 4 + qq, kt = sk * 4 + kk;

  const int tid  = threadIdx.x;
  const int lane = tid & 63;
  const int w    = tid >> 6;
  const int wm   = w >> 2, wn = w & 3;
  const int lrow = lane & 15;
  const int crow = (lane >> 4) * 4;

  const char* Ab = (const char*)(Z + ((size_t)b * Tn + qt * 256) * Cn);
  const char* Bb = (const char*)(X + ((size_t)b * Tn + kt * 256) * Cn);

  f32x4 acc[8][4] = {};
  gemm_core(Ab, Bb, lds, tid, acc);

  const float kf = 0.036084391824351615f * 1.4426950408889634f;  // scale * log2(e)
  float vv[4];
#pragma unroll
  for (int ni = 0; ni < 4; ++ni)
    vv[ni] = v[(size_t)b * Tn + kt * 256 + wn * 64 + ni * 16 + lrow];

  float csum[4] = {0.f, 0.f, 0.f, 0.f};
#pragma unroll
  for (int mi = 0; mi < 8; ++mi) {
    const f32x4 uu = *(const f32x4*)&u[(size_t)b * Tn + qt * 256 + wm * 128 +
                                       (mi >> 2) * 64 + (mi & 3) * 16 + crow];
#pragma unroll
    for (int ni = 0; ni < 4; ++ni)
#pragma unroll
      for (int rr = 0; rr < 4; ++rr) {
        const float e = __builtin_amdgcn_exp2f(-(acc[mi][ni][rr] + uu[rr] + vv[ni]) * kf);
        csum[ni] += __builtin_amdgcn_rcpf(1.f + e);
      }
  }
#pragma unroll
  for (int ni = 0; ni < 4; ++ni) {
    csum[ni] += __shfl_xor(csum[ni], 16);
    csum[ni] += __shfl_xor(csum[ni], 32);
  }
  if (lane < 16) {
#pragma unroll
    for (int ni = 0; ni < 4; ++ni)
      atomicAdd(&wsum[(size_t)b * Tn + kt * 256 + wn * 64 + ni * 16 + lane], csum[ni]);
  }
}

// ---------------- small kernels ----------------

// 32x32 LDS transpose: W[d][c] fp32 -> WT[c][d] bf16 (for Wq and Wk)
__global__ __launch_bounds__(256)
void cvt_wt(const float* __restrict__ Wq, const float* __restrict__ Wk,
            __bf16* __restrict__ WqT, __bf16* __restrict__ WkT)
{
  __shared__ float tile[32][33];
  const float* src = blockIdx.z ? Wk : Wq;
  __bf16*      dst = blockIdx.z ? WkT : WqT;
  const int d0 = blockIdx.x * 32, c0 = blockIdx.y * 32;
  const int t = threadIdx.x, rr = t >> 3, c4 = (t & 7) * 4;
  const float4v vv = *(const float4v*)&src[(size_t)(d0 + rr) * 768 + c0 + c4];
#pragma unroll
  for (int j = 0; j < 4; ++j) tile[rr][c4 + j] = vv[j];
  __syncthreads();
  short4v s;
#pragma unroll
  for (int j = 0; j < 4; ++j)
    s[j] = __builtin_bit_cast(short, __float2bfloat16(tile[c4 + j][rr]));
  *(short4v*)&dst[(size_t)(c0 + rr) * 768 + d0 + c4] = s;
}

// wqbk[c] = sum_d Wq[d,c]*bk[d];  wkbq[c] = sum_d Wk[d,c]*bq[d];  c0 = bq.bk
__global__ __launch_bounds__(256)
void biasprep(const float* __restrict__ Wq, const float* __restrict__ Wk,
              const float* __restrict__ bq, const float* __restrict__ bk,
              float* __restrict__ wqbk, float* __restrict__ wkbq, float* __restrict__ c0p)
{
  const int t = threadIdx.x, bid = blockIdx.x;
  if (bid < 24) {
    float aq[3] = {}, ak[3] = {};
    const int d0 = bid * 32;
    for (int dd = 0; dd < 32; ++dd) {
      const int d = d0 + dd;
      const float bkd = bk[d], bqd = bq[d];
#pragma unroll
      for (int i = 0; i < 3; ++i) {
        aq[i] += Wq[(size_t)d * 768 + t + i * 256] * bkd;
        ak[i] += Wk[(size_t)d * 768 + t + i * 256] * bqd;
      }
    }
#pragma unroll
    for (int i = 0; i < 3; ++i) {
      atomicAdd(&wqbk[t + i * 256], aq[i]);
      atomicAdd(&wkbq[t + i * 256], ak[i]);
    }
  } else {
    float s = 0.f;
#pragma unroll
    for (int i = 0; i < 3; ++i) { const int d = t + i * 256; s += bq[d] * bk[d]; }
#pragma unroll
    for (int off = 32; off; off >>= 1) s += __shfl_down(s, off);
    __shared__ float rr[4];
    if ((t & 63) == 0) rr[t >> 6] = s;
    __syncthreads();
    if (t == 0) atomicAdd(c0p, rr[0] + rr[1] + rr[2] + rr[3]);
  }
}

// Gt[c'][c] = sum_d Wk[d,c']*Wq[d,c]  -- 128x128-tile 2-phase mini GEMM (A=WkT, B=WqT)
__device__ __forceinline__ void stage128(const char* gbase, __bf16* lds_, int t) {
#pragma unroll
  for (int i = 0; i < 4; ++i) {
    const int O   = i * 4096 + t * 16;
    const int row = O >> 7;
    const int cb  = O & 127;
    gload_lds16(gbase + (size_t)row * 1536 + cb, (char*)lds_ + O);
  }
}

__global__ __launch_bounds__(256, 2)
void gt_kernel(const __bf16* __restrict__ A, const __bf16* __restrict__ B,
               __bf16* __restrict__ Gt)
{
  __shared__ __bf16 As[128 * 64];
  __shared__ __bf16 Bs[128 * 64];
  const int t = threadIdx.x;
  const int tile_n = (blockIdx.x % 6) * 128, tile_m = (blockIdx.x / 6) * 128;
  const int lane = t & 63, wv = t >> 6;
  const int wm = wv >> 1, wn = wv & 1;
  const int lrow = lane & 15, lk8 = (lane >> 4) * 8, crow = (lane >> 4) * 4;

  const char* Ab = (const char*)(A + (size_t)tile_m * 768);
  const char* Bb = (const char*)(B + (size_t)tile_n * 768);

  f32x4 acc[4][4] = {};
  for (int k0 = 0; k0 < 768; k0 += 64) {
    stage128(Ab + (size_t)k0 * 2, As, t);
    stage128(Bb + (size_t)k0 * 2, Bs, t);
    __syncthreads();
#pragma unroll
    for (int ks = 0; ks < 2; ++ks) {
      bf16x8 a[4], bb[4];
#pragma unroll
      for (int mi = 0; mi < 4; ++mi)
        a[mi] = *(const bf16x8*)&As[(wm * 64 + mi * 16 + lrow) * 64 + ks * 32 + lk8];
#pragma unroll
      for (int ni = 0; ni < 4; ++ni)
        bb[ni] = *(const bf16x8*)&Bs[(wn * 64 + ni * 16 + lrow) * 64 + ks * 32 + lk8];
#pragma unroll
      for (int mi = 0; mi < 4; ++mi)
#pragma unroll
        for (int ni = 0; ni < 4; ++ni)
          acc[mi][ni] = MFMA16x16(a[mi], bb[ni], acc[mi][ni]);
    }
    __syncthreads();
  }
#pragma unroll
  for (int mi = 0; mi < 4; ++mi)
#pragma unroll
    for (int ni = 0; ni < 4; ++ni)
#pragma unroll
      for (int r = 0; r < 4; ++r)
        Gt[(size_t)(tile_m + wm * 64 + mi * 16 + crow + r) * 768 +
           tile_n + wn * 64 + ni * 16 + lrow] = (__bf16)acc[mi][ni][r];
}

// ---------------- cvt x->bf16 fused with u = x.wqbk + c0, v = x.wkbq (one wave per row)
__global__ __launch_bounds__(512)
void cvt_x_uv(const float* __restrict__ x, const float* __restrict__ wqbk,
              const float* __restrict__ wkbq, const float* __restrict__ c0p,
              __hip_bfloat16* __restrict__ xb, float* __restrict__ u, float* __restrict__ v)
{
  __shared__ float wq_l[768], wk_l[768];
  const int t = threadIdx.x;
  for (int i = t; i < 768; i += 512) { wq_l[i] = wqbk[i]; wk_l[i] = wkbq[i]; }
  __syncthreads();
  const int lane = t & 63, wv = t >> 6;
  const int row = blockIdx.x * 8 + wv;
  const float4v* xr = (const float4v*)(x + (size_t)row * 768);
  short4v* xo = (short4v*)((__bf16*)xb + (size_t)row * 768);
  float du = 0.f, dv = 0.f;
#pragma unroll
  for (int i = 0; i < 3; ++i) {
    const int ch = lane + 64 * i;
    const float4v xv = xr[ch];
    short4v s;
#pragma unroll
    for (int j = 0; j < 4; ++j) {
      s[j] = __builtin_bit_cast(short, __float2bfloat16(xv[j]));
      du += xv[j] * wq_l[ch * 4 + j];
      dv += xv[j] * wk_l[ch * 4 + j];
    }
    xo[ch] = s;
  }
#pragma unroll
  for (int off = 1; off < 64; off <<= 1) {
    du += __shfl_xor(du, off);
    dv += __shfl_xor(dv, off);
  }
  if (lane == 0) { u[row] = du + *c0p; v[row] = dv; }
}

// ---------------- y[b,c] = sum_k w[b,k] * x[b,k,c]  (fp32 x, fp32 accum)
__global__ __launch_bounds__(192)
void wx_kernel(const float* __restrict__ w, const float* __restrict__ x,
               float* __restrict__ y)
{
  const int b = blockIdx.x, ks = blockIdx.y;
  const int t = threadIdx.x;
  const float*  wr = w + (size_t)b * Tn + ks * 64;
  const float4v* xr = (const float4v*)(x + ((size_t)b * Tn + (size_t)ks * 64) * Cn);
  float4v acc = {};
#pragma unroll 4
  for (int k = 0; k < 64; ++k) {
    const float wk = wr[k];
    const float4v xv = xr[(size_t)k * 192 + t];
#pragma unroll
    for (int j = 0; j < 4; ++j) acc[j] += wk * xv[j];
  }
  float* yb = y + (size_t)b * Cn + t * 4;
#pragma unroll
  for (int j = 0; j < 4; ++j) atomicAdd(yb + j, acc[j]);
}

// ---------------- out_pre[b,d] = ( y[b,:].Wv[d,:] + sw[b]*bv[d] ) / T
__global__ __launch_bounds__(256)
void vproj_kernel(const float* __restrict__ y, const float* __restrict__ wsum,
                  const float* __restrict__ Wv, const float* __restrict__ bv,
                  float* __restrict__ opre)
{
  __shared__ float ys[Cn];
  __shared__ float red[4];
  const int b = blockIdx.x, t = threadIdx.x;
  float s = 0.f;
  for (int i = t; i < Tn; i += 256) s += wsum[(size_t)b * Tn + i];
#pragma unroll
  for (int off = 32; off; off >>= 1) s += __shfl_down(s, off);
  if ((t & 63) == 0) red[t >> 6] = s;
  for (int i = t; i < Cn; i += 256) ys[i] = y[(size_t)b * Cn + i];
  __syncthreads();
  const float sw = red[0] + red[1] + red[2] + red[3];
  const float4v* ysv = (const float4v*)ys;
#pragma unroll
  for (int dd = 0; dd < 3; ++dd) {
    const int d = t + dd * 256;
    const float4v* wrow = (const float4v*)(Wv + (size_t)d * Cn);
    float4v a = {};
    for (int c = 0; c < Cn / 4; ++c) {
      const float4v wv4 = wrow[c];
      const float4v yv4 = ysv[c];
#pragma unroll
      for (int j = 0; j < 4; ++j) a[j] += wv4[j] * yv4[j];
    }
    const float dot = a[0] + a[1] + a[2] + a[3];
    opre[(size_t)b * Cn + d] = (dot + sw * bv[d]) * (1.f / 2048.f);
  }
}

// ---------------- BatchNorm1d over batch dim
__global__ void bn_kernel(const float* __restrict__ out_pre,
                          const float* __restrict__ gamma, const float* __restrict__ beta,
                          float* __restrict__ out)
{
  const int d = blockIdx.x * 256 + threadIdx.x;
  float vals[16];
  float s = 0.f;
#pragma unroll
  for (int b = 0; b < 16; ++b) { vals[b] = out_pre[b * Cn + d]; s += vals[b]; }
  const float mu = s * (1.f / 16.f);
  float s2 = 0.f;
#pragma unroll
  for (int b = 0; b < 16; ++b) { float t2 = vals[b] - mu; s2 += t2 * t2; }
  const float inv = rsqrtf(s2 * (1.f / 16.f) + 1e-5f);
  const float g = gamma[d] * inv, be = beta[d];
#pragma unroll
  for (int b = 0; b < 16; ++b) out[b * Cn + d] = (vals[b] - mu) * g + be;
}

extern "C" void kernel_launch(void* const* d_in, const int* in_sizes, int n_in,
                              void* d_out, int out_size, void* d_ws, size_t ws_size,
                              hipStream_t stream)
{
  const float* x  = (const float*)d_in[0];
  const float* Wq = (const float*)d_in[1];
  const float* bq = (const float*)d_in[2];
  const float* Wk = (const float*)d_in[3];
  const float* bk = (const float*)d_in[4];
  const float* Wv = (const float*)d_in[5];
  const float* bv = (const float*)d_in[6];
  const float* gamma = (const float*)d_in[7];
  const float* beta  = (const float*)d_in[8];
  float* out = (float*)d_out;

  char* ws = (char*)d_ws;
  // workspace layout (~104.7 MiB)
  __hip_bfloat16* xb  = (__hip_bfloat16*)(ws);                  // 32768*768*2 = 50,331,648
  __hip_bfloat16* Zb  = (__hip_bfloat16*)(ws + 50331648);       // 50,331,648
  __bf16*         WqT = (__bf16*)        (ws + 100663296);      //  1,179,648
  __bf16*         WkT = (__bf16*)        (ws + 101842944);      //  1,179,648
  __bf16*         Gt  = (__bf16*)        (ws + 103022592);      //  1,179,648
  float*          u   = (float*)         (ws + 104202240);      //    131,072
  float*          v   = (float*)         (ws + 104333312);      //    131,072
  float*          wsum= (float*)         (ws + 104464384);      //    131,072  <- zeroed from here
  float*          yv  = (float*)         (ws + 104595456);      //     49,152
  float*          opre= (float*)         (ws + 104644608);      //     49,152
  float*          wqbk= (float*)         (ws + 104693760);      //      3,072
  float*          wkbq= (float*)         (ws + 104696832);      //      3,072
  float*          c0p = (float*)         (ws + 104699904);      //          4

  (void)in_sizes; (void)n_in; (void)out_size; (void)ws_size;

  hipMemsetAsync(wsum, 0, 235524, stream);  // wsum + yv + opre + wqbk + wkbq + c0

  cvt_wt<<<dim3(24, 24, 2), 256, 0, stream>>>(Wq, Wk, WqT, WkT);
  biasprep<<<dim3(25), 256, 0, stream>>>(Wq, Wk, bq, bk, wqbk, wkbq, c0p);
  gt_kernel<<<dim3(36), 256, 0, stream>>>(WkT, WqT, Gt);
  cvt_x_uv<<<dim3(4096), 512, 0, stream>>>(x, wqbk, wkbq, c0p, xb, u, v);

  z_kernel<<<dim3(384), 512, 0, stream>>>((const __bf16*)xb, Gt, Zb);

  attn_kernel<<<dim3(1024), 512, 0, stream>>>(
      (const __bf16*)Zb, (const __bf16*)xb, u, v, wsum);

  wx_kernel<<<dim3(Bn, 32), 192, 0, stream>>>(wsum, x, yv);
  vproj_kernel<<<dim3(Bn), 256, 0, stream>>>(yv, wsum, Wv, bv, opre);
  bn_kernel<<<dim3(3), 256, 0, stream>>>(opre, gamma, beta, out);
}

// Round 5
// 262.322 us; speedup vs baseline: 1.3456x; 1.2173x over previous
//
#include <hip/hip_runtime.h>
#include <hip/hip_bf16.h>

typedef __bf16 bf16x8 __attribute__((ext_vector_type(8)));
typedef float  f32x4  __attribute__((ext_vector_type(4)));
typedef float  float4v __attribute__((ext_vector_type(4)));
typedef short  short4v __attribute__((ext_vector_type(4)));

static constexpr int Tn  = 2048;
static constexpr int Bn  = 16;
static constexpr int Cn  = 768;
static constexpr int KT  = 12;       // 768 / 64 K-steps

#define MFMA16x16(a, b, c) __builtin_amdgcn_mfma_f32_16x16x32_bf16(a, b, c, 0, 0, 0)

__device__ __forceinline__ void gload_lds16(const void* g, void* l) {
  __builtin_amdgcn_global_load_lds((const __attribute__((address_space(1))) void*)g,
                                   (__attribute__((address_space(3))) void*)l, 16, 0, 0);
}

// Stage one 16KB unit: [256 rows][32 bf16 = 64B], global row stride 1536B.
// LDS dest linear; global source pre-inverse-swizzled (involution, 16B granules).
__device__ __forceinline__ void stage_unit(const char* gk, char* ldsu, int tid) {
#pragma unroll
  for (int c = 0; c < 2; ++c) {
    const int o   = tid * 16 + c * 8192;
    const int row = o >> 6;
    const int col = (o & 63) ^ (((o >> 7) & 3) << 4);
    gload_lds16(gk + (size_t)row * 1536 + col, ldsu + o);
  }
}

// 24KB unit: [384 rows][64B] (3 x 16B per thread)
__device__ __forceinline__ void stage_unitB(const char* gk, char* ldsu, int tid) {
#pragma unroll
  for (int c = 0; c < 3; ++c) {
    const int o   = tid * 16 + c * 8192;
    const int row = o >> 6;
    const int col = (o & 63) ^ (((o >> 7) & 3) << 4);
    gload_lds16(gk + (size_t)row * 1536 + col, ldsu + o);
  }
}

__device__ __forceinline__ bf16x8 frag_ld(const char* unit, int r, int lcb) {
  return *(const bf16x8*)(unit + r * 64 + (lcb ^ (((r >> 1) & 3) << 4)));
}

#define DS_WAIT do { asm volatile("s_waitcnt lgkmcnt(0)" ::: "memory"); \
                     __builtin_amdgcn_sched_barrier(0); } while (0)

// ---------------- persistent attention colsum:
// wsum[b,k] += sum_q sigmoid(scale*(Z_q.X_k + u_q + v_k)); 256 blocks, 4 chained kt-tiles.
__global__ __launch_bounds__(512, 2)
void attn_kernel(const __bf16* __restrict__ Z, const __bf16* __restrict__ X,
                 const float* __restrict__ u, const float* __restrict__ v,
                 float* __restrict__ wsum)
{
  __shared__ char lds[131072];
  const int i   = blockIdx.x;          // 256
  const int xcd = i & 7, j = i >> 3;   // j 0..31
  const int b    = xcd * 2 + (j >> 4);
  const int qt   = (j >> 1) & 7;
  const int half = j & 1;              // kt in {half*4 .. half*4+3}

  const int tid  = threadIdx.x;
  const int lane = tid & 63;
  const int w    = tid >> 6;
  const int wm   = w >> 2, wn = w & 3;
  const int lrow = lane & 15;
  const int lcb  = (lane >> 4) * 16;
  const int ar   = wm * 128 + lrow;
  const int br   = wn * 64 + lrow;
  const int crow = (lane >> 4) * 4;

  const char* Ab  = (const char*)(Z + ((size_t)b * Tn + qt * 256) * Cn);
  const char* Xb0 = (const char*)(X + ((size_t)b * Tn + (size_t)(half * 4) * 256) * Cn);

  // prologue: stage tile0 chunk0
  stage_unit(Ab,       lds + 0,     tid);
  stage_unit(Xb0,      lds + 32768, tid);
  stage_unit(Ab + 64,  lds + 16384, tid);
  stage_unit(Xb0 + 64, lds + 49152, tid);
  asm volatile("s_waitcnt vmcnt(0)" ::: "memory");
  __builtin_amdgcn_s_barrier();

  const float kf = 0.036084391824351615f * 1.4426950408889634f;  // scale * log2(e)

#pragma unroll 1
  for (int tt = 0; tt < 4; ++tt) {
    const int kt = half * 4 + tt;
    f32x4 acc[8][4] = {};

    for (int t = 0; t < KT; ++t) {
      const int g  = tt * KT + t;
      const int h  = g + 1;
      const bool st = (h < 4 * KT);
      const int ht = h / KT;
      const int hc = h - ht * KT;
      const char* bp = lds + (g & 1) * 65536;
      char*       bq = lds + (h & 1) * 65536;
      const char* gA = Ab + (size_t)hc * 128;
      const char* gB = Xb0 + (size_t)ht * 393216 + (size_t)hc * 128;
      bf16x8 aF[4], bF[4];

      // phase 0: ks0, mh0; stage A-ks0(h)
#pragma unroll
      for (int i2 = 0; i2 < 4; ++i2) bF[i2] = frag_ld(bp + 32768, br + i2 * 16, lcb);
#pragma unroll
      for (int i2 = 0; i2 < 4; ++i2) aF[i2] = frag_ld(bp, ar + i2 * 16, lcb);
      if (st) stage_unit(gA, bq, tid);
      __builtin_amdgcn_s_barrier();
      DS_WAIT;
      __builtin_amdgcn_s_setprio(1);
#pragma unroll
      for (int i2 = 0; i2 < 4; ++i2)
#pragma unroll
        for (int j2 = 0; j2 < 4; ++j2)
          acc[i2][j2] = MFMA16x16(aF[i2], bF[j2], acc[i2][j2]);
      __builtin_amdgcn_s_setprio(0);
      __builtin_amdgcn_s_barrier();

      // phase 1: ks0, mh1; stage B-ks0(h); counted vmcnt
#pragma unroll
      for (int i2 = 0; i2 < 4; ++i2) aF[i2] = frag_ld(bp, ar + 64 + i2 * 16, lcb);
      if (st) { stage_unit(gB, bq + 32768, tid);
                asm volatile("s_waitcnt vmcnt(4)" ::: "memory"); }
      else    { asm volatile("s_waitcnt vmcnt(0)" ::: "memory"); }
      __builtin_amdgcn_s_barrier();
      DS_WAIT;
      __builtin_amdgcn_s_setprio(1);
#pragma unroll
      for (int i2 = 0; i2 < 4; ++i2)
#pragma unroll
        for (int j2 = 0; j2 < 4; ++j2)
          acc[4 + i2][j2] = MFMA16x16(aF[i2], bF[j2], acc[4 + i2][j2]);
      __builtin_amdgcn_s_setprio(0);
      __builtin_amdgcn_s_barrier();

      // phase 2: ks1, mh0; stage A-ks1(h)
#pragma unroll
      for (int i2 = 0; i2 < 4; ++i2) bF[i2] = frag_ld(bp + 49152, br + i2 * 16, lcb);
#pragma unroll
      for (int i2 = 0; i2 < 4; ++i2) aF[i2] = frag_ld(bp + 16384, ar + i2 * 16, lcb);
      if (st) stage_unit(gA + 64, bq + 16384, tid);
      __builtin_amdgcn_s_barrier();
      DS_WAIT;
      __builtin_amdgcn_s_setprio(1);
#pragma unroll
      for (int i2 = 0; i2 < 4; ++i2)
#pragma unroll
        for (int j2 = 0; j2 < 4; ++j2)
          acc[i2][j2] = MFMA16x16(aF[i2], bF[j2], acc[i2][j2]);
      __builtin_amdgcn_s_setprio(0);
      __builtin_amdgcn_s_barrier();

      // phase 3: ks1, mh1; stage B-ks1(h); counted vmcnt
#pragma unroll
      for (int i2 = 0; i2 < 4; ++i2) aF[i2] = frag_ld(bp + 16384, ar + 64 + i2 * 16, lcb);
      if (st) { stage_unit(gB + 64, bq + 49152, tid);
                asm volatile("s_waitcnt vmcnt(4)" ::: "memory"); }
      else    { asm volatile("s_waitcnt vmcnt(0)" ::: "memory"); }
      __builtin_amdgcn_s_barrier();
      DS_WAIT;
      __builtin_amdgcn_s_setprio(1);
#pragma unroll
      for (int i2 = 0; i2 < 4; ++i2)
#pragma unroll
        for (int j2 = 0; j2 < 4; ++j2)
          acc[4 + i2][j2] = MFMA16x16(aF[i2], bF[j2], acc[4 + i2][j2]);
      __builtin_amdgcn_s_setprio(0);
      __builtin_amdgcn_s_barrier();
    }

    // per-tile epilogue: sigmoid + column-sum + atomics (no LDS use)
    float vv[4];
#pragma unroll
    for (int ni = 0; ni < 4; ++ni)
      vv[ni] = v[(size_t)b * Tn + kt * 256 + wn * 64 + ni * 16 + lrow];

    float csum[4] = {0.f, 0.f, 0.f, 0.f};
#pragma unroll
    for (int mi = 0; mi < 8; ++mi) {
      const f32x4 uu = *(const f32x4*)&u[(size_t)b * Tn + qt * 256 + wm * 128 +
                                         (mi >> 2) * 64 + (mi & 3) * 16 + crow];
#pragma unroll
      for (int ni = 0; ni < 4; ++ni)
#pragma unroll
        for (int rr = 0; rr < 4; ++rr) {
          const float e = __builtin_amdgcn_exp2f(-(acc[mi][ni][rr] + uu[rr] + vv[ni]) * kf);
          csum[ni] += __builtin_amdgcn_rcpf(1.f + e);
        }
    }
#pragma unroll
    for (int ni = 0; ni < 4; ++ni) {
      csum[ni] += __shfl_xor(csum[ni], 16);
      csum[ni] += __shfl_xor(csum[ni], 32);
    }
    if (lane < 16) {
#pragma unroll
      for (int ni = 0; ni < 4; ++ni)
        atomicAdd(&wsum[(size_t)b * Tn + kt * 256 + wn * 64 + ni * 16 + lane], csum[ni]);
    }
  }
}

// ---------------- Z = X * Gt^T: 256x384 tiles, 256 blocks, one round
__global__ __launch_bounds__(512, 2)
void z_kernel(const __bf16* __restrict__ X, const __bf16* __restrict__ Gt,
              __hip_bfloat16* __restrict__ Zo)
{
  __shared__ char lds[163840];   // 2 x (A 2x16KB + B 2x24KB) = 2 x 80KB
  int f = blockIdx.x;            // 256
  f = (f & 7) * 32 + (f >> 3);   // XCD-chunked
  const int tn = f & 1, tm = f >> 1;
  const int tile_m = tm * 256, tile_n = tn * 384;

  const int tid  = threadIdx.x;
  const int lane = tid & 63;
  const int w    = tid >> 6;
  const int wm   = w >> 2, wn = w & 3;   // wave tile 128x96
  const int lrow = lane & 15;
  const int lcb  = (lane >> 4) * 16;
  const int ar   = wm * 128 + lrow;
  const int br   = wn * 96 + lrow;
  // swizzle XOR is invariant under +16*i (8i = 0 mod 4) -> base + i*1024 immediates
  const int aB = ar * 64 + (lcb ^ (((ar >> 1) & 3) << 4));
  const int bB = br * 64 + (lcb ^ (((br >> 1) & 3) << 4));

  const char* Ab = (const char*)(X + (size_t)tile_m * Cn);
  const char* Bb = (const char*)(Gt + (size_t)tile_n * Cn);

  f32x4 acc[8][6] = {};

  stage_unit (Ab,      lds + 0,     tid);
  stage_unitB(Bb,      lds + 32768, tid);
  stage_unit (Ab + 64, lds + 16384, tid);
  stage_unitB(Bb + 64, lds + 57344, tid);
  asm volatile("s_waitcnt vmcnt(0)" ::: "memory");
  __builtin_amdgcn_s_barrier();

  for (int t = 0; t < KT; ++t) {
    const char* bp = lds + (t & 1) * 81920;
    char*       bq = lds + ((t + 1) & 1) * 81920;
    const char* gA = Ab + (size_t)(t + 1) * 128;
    const char* gB = Bb + (size_t)(t + 1) * 128;
    const bool st  = (t < KT - 1);
    bf16x8 aF[4], bF[6];

    // p0: bF(ks0) + aF mh0(ks0); stage A-ks0
#pragma unroll
    for (int i2 = 0; i2 < 6; ++i2) bF[i2] = *(const bf16x8*)(bp + 32768 + bB + i2 * 1024);
#pragma unroll
    for (int i2 = 0; i2 < 4; ++i2) aF[i2] = *(const bf16x8*)(bp + aB + i2 * 1024);
    if (st) stage_unit(gA, bq, tid);
    __builtin_amdgcn_s_barrier();
    DS_WAIT;
    __builtin_amdgcn_s_setprio(1);
#pragma unroll
    for (int i2 = 0; i2 < 4; ++i2)
#pragma unroll
      for (int j2 = 0; j2 < 6; ++j2)
        acc[i2][j2] = MFMA16x16(aF[i2], bF[j2], acc[i2][j2]);
    __builtin_amdgcn_s_setprio(0);
    __builtin_amdgcn_s_barrier();

    // p1: aF mh1(ks0); stage B-ks0; vmcnt(5)
#pragma unroll
    for (int i2 = 0; i2 < 4; ++i2) aF[i2] = *(const bf16x8*)(bp + aB + 4096 + i2 * 1024);
    if (st) { stage_unitB(gB, bq + 32768, tid);
              asm volatile("s_waitcnt vmcnt(5)" ::: "memory"); }
    else    { asm volatile("s_waitcnt vmcnt(0)" ::: "memory"); }
    __builtin_amdgcn_s_barrier();
    DS_WAIT;
    __builtin_amdgcn_s_setprio(1);
#pragma unroll
    for (int i2 = 0; i2 < 4; ++i2)
#pragma unroll
      for (int j2 = 0; j2 < 6; ++j2)
        acc[4 + i2][j2] = MFMA16x16(aF[i2], bF[j2], acc[4 + i2][j2]);
    __builtin_amdgcn_s_setprio(0);
    __builtin_amdgcn_s_barrier();

    // p2: bF(ks1) + aF mh0(ks1); stage A-ks1
#pragma unroll
    for (int i2 = 0; i2 < 6; ++i2) bF[i2] = *(const bf16x8*)(bp + 57344 + bB + i2 * 1024);
#pragma unroll
    for (int i2 = 0; i2 < 4; ++i2) aF[i2] = *(const bf16x8*)(bp + 16384 + aB + i2 * 1024);
    if (st) stage_unit(gA + 64, bq + 16384, tid);
    __builtin_amdgcn_s_barrier();
    DS_WAIT;
    __builtin_amdgcn_s_setprio(1);
#pragma unroll
    for (int i2 = 0; i2 < 4; ++i2)
#pragma unroll
      for (int j2 = 0; j2 < 6; ++j2)
        acc[i2][j2] = MFMA16x16(aF[i2], bF[j2], acc[i2][j2]);
    __builtin_amdgcn_s_setprio(0);
    __builtin_amdgcn_s_barrier();

    // p3: aF mh1(ks1); stage B-ks1; vmcnt(5)
#pragma unroll
    for (int i2 = 0; i2 < 4; ++i2) aF[i2] = *(const bf16x8*)(bp + 16384 + aB + 4096 + i2 * 1024);
    if (st) { stage_unitB(gB + 64, bq + 57344, tid);
              asm volatile("s_waitcnt vmcnt(5)" ::: "memory"); }
    else    { asm volatile("s_waitcnt vmcnt(0)" ::: "memory"); }
    __builtin_amdgcn_s_barrier();
    DS_WAIT;
    __builtin_amdgcn_s_setprio(1);
#pragma unroll
    for (int i2 = 0; i2 < 4; ++i2)
#pragma unroll
      for (int j2 = 0; j2 < 6; ++j2)
        acc[4 + i2][j2] = MFMA16x16(aF[i2], bF[j2], acc[4 + i2][j2]);
    __builtin_amdgcn_s_setprio(0);
    __builtin_amdgcn_s_barrier();
  }

  // epilogue: banded LDS repack [64][392 bf16] -> coalesced stores
  __bf16* cb = (__bf16*)lds;
  const int crow = (lane >> 4) * 4;
  for (int rb = 0; rb < 4; ++rb) {
    __syncthreads();
    if (wm == (rb >> 1)) {
#pragma unroll
      for (int mi2 = 0; mi2 < 4; ++mi2) {
        const int mi = (rb & 1) * 4 + mi2;
        const int lr = mi2 * 16 + crow;
#pragma unroll
        for (int ni = 0; ni < 6; ++ni) {
          const int col = wn * 96 + ni * 16 + lrow;
#pragma unroll
          for (int r = 0; r < 4; ++r)
            cb[(lr + r) * 392 + col] = (__bf16)acc[mi][ni][r];
        }
      }
    }
    __syncthreads();
    const int row = tid >> 3;
    const int seg = tid & 7;
    char* gout = (char*)Zo + (size_t)(tile_m + rb * 64 + row) * 1536 + tile_n * 2 + seg * 96;
    const char* lsrc = (const char*)cb + row * 784 + seg * 96;
#pragma unroll
    for (int i2 = 0; i2 < 6; ++i2)
      *(float4v*)(gout + i2 * 16) = *(const float4v*)(lsrc + i2 * 16);
  }
}

// ---------------- Gt[c'][c] = sum_d Wk[d,c']*Wq[d,c], fp32 in (transpose via LDS), bf16 out
__global__ __launch_bounds__(256)
void gt_kernel(const float* __restrict__ Wk, const float* __restrict__ Wq,
               __bf16* __restrict__ Gt)
{
  __shared__ __bf16 ak[64 * 40], bkl[64 * 40];   // [col][d], stride 40 (80B, 16B-aligned)
  const int t  = threadIdx.x;
  const int tm = (blockIdx.x / 12) * 64;   // c' tile
  const int tn = (blockIdx.x % 12) * 64;   // c  tile
  const int lane = t & 63, w = t >> 6;
  const int wm = w >> 1, wn = w & 1;       // 2x2 waves of 32x32
  const int lrow = lane & 15, lk8 = (lane >> 4) * 8, crow = (lane >> 4) * 4;
  const int lc = t & 63, ld = t >> 6;
  f32x4 acc[2][2] = {};

  for (int d0 = 0; d0 < 768; d0 += 32) {
    __syncthreads();
#pragma unroll
    for (int dd = 0; dd < 8; ++dd) {
      const int dl = ld + dd * 4;
      ak [lc * 40 + dl] = (__bf16)Wk[(size_t)(d0 + dl) * 768 + tm + lc];
      bkl[lc * 40 + dl] = (__bf16)Wq[(size_t)(d0 + dl) * 768 + tn + lc];
    }
    __syncthreads();
    bf16x8 a[2], b2[2];
#pragma unroll
    for (int mi = 0; mi < 2; ++mi)
      a[mi] = *(const bf16x8*)&ak[(wm * 32 + mi * 16 + lrow) * 40 + lk8];
#pragma unroll
    for (int ni = 0; ni < 2; ++ni)
      b2[ni] = *(const bf16x8*)&bkl[(wn * 32 + ni * 16 + lrow) * 40 + lk8];
#pragma unroll
    for (int mi = 0; mi < 2; ++mi)
#pragma unroll
      for (int ni = 0; ni < 2; ++ni)
        acc[mi][ni] = MFMA16x16(a[mi], b2[ni], acc[mi][ni]);
  }
#pragma unroll
  for (int mi = 0; mi < 2; ++mi)
#pragma unroll
    for (int ni = 0; ni < 2; ++ni)
#pragma unroll
      for (int r = 0; r < 4; ++r)
        Gt[(size_t)(tm + wm * 32 + mi * 16 + crow + r) * 768 +
           tn + wn * 32 + ni * 16 + lrow] = (__bf16)acc[mi][ni][r];
}

// ---------------- wqbk[c] = sum_d Wq[d,c]*bk[d]; wkbq[c] = sum_d Wk[d,c]*bq[d]; c0 = bq.bk
__global__ __launch_bounds__(256)
void biasprep(const float* __restrict__ Wq, const float* __restrict__ Wk,
              const float* __restrict__ bq, const float* __restrict__ bk,
              float* __restrict__ wqbk, float* __restrict__ wkbq, float* __restrict__ c0p)
{
  const int t = threadIdx.x, bx = blockIdx.x, by = blockIdx.y;
  if (by == 32) {
    if (bx == 0) {
      float s = 0.f;
#pragma unroll
      for (int i2 = 0; i2 < 3; ++i2) { const int d = t + i2 * 256; s += bq[d] * bk[d]; }
#pragma unroll
      for (int off = 32; off; off >>= 1) s += __shfl_down(s, off);
      __shared__ float rr[4];
      if ((t & 63) == 0) rr[t >> 6] = s;
      __syncthreads();
      if (t == 0) atomicAdd(c0p, rr[0] + rr[1] + rr[2] + rr[3]);
    }
    return;
  }
  const int c = bx * 256 + t;
  float aq = 0.f, ak2 = 0.f;
  for (int dd = 0; dd < 24; ++dd) {
    const int d = by * 24 + dd;
    aq  += Wq[(size_t)d * 768 + c] * bk[d];
    ak2 += Wk[(size_t)d * 768 + c] * bq[d];
  }
  atomicAdd(&wqbk[c], aq);
  atomicAdd(&wkbq[c], ak2);
}

// ---------------- cvt x->bf16 fused with u = x.wqbk + c0, v = x.wkbq
__global__ __launch_bounds__(512)
void cvt_x_uv(const float* __restrict__ x, const float* __restrict__ wqbk,
              const float* __restrict__ wkbq, const float* __restrict__ c0p,
              __hip_bfloat16* __restrict__ xb, float* __restrict__ u, float* __restrict__ v)
{
  __shared__ float wq_l[768], wk_l[768];
  const int t = threadIdx.x;
  for (int i = t; i < 768; i += 512) { wq_l[i] = wqbk[i]; wk_l[i] = wkbq[i]; }
  __syncthreads();
  const int lane = t & 63, wv = t >> 6;
  const int row = blockIdx.x * 8 + wv;
  const float4v* xr = (const float4v*)(x + (size_t)row * 768);
  short4v* xo = (short4v*)((__bf16*)xb + (size_t)row * 768);
  float du = 0.f, dv = 0.f;
#pragma unroll
  for (int i = 0; i < 3; ++i) {
    const int ch = lane + 64 * i;
    const float4v xv = xr[ch];
    short4v s;
#pragma unroll
    for (int j = 0; j < 4; ++j) {
      s[j] = __builtin_bit_cast(short, __float2bfloat16(xv[j]));
      du += xv[j] * wq_l[ch * 4 + j];
      dv += xv[j] * wk_l[ch * 4 + j];
    }
    xo[ch] = s;
  }
#pragma unroll
  for (int off = 1; off < 64; off <<= 1) {
    du += __shfl_xor(du, off);
    dv += __shfl_xor(dv, off);
  }
  if (lane == 0) { u[row] = du + *c0p; v[row] = dv; }
}

// ---------------- y[b,c] = sum_k w[b,k]*xb[b,k,c]; sw[b] = sum_k w[b,k]
__global__ __launch_bounds__(192)
void wx_kernel(const float* __restrict__ wsum, const __bf16* __restrict__ xb,
               float* __restrict__ y, float* __restrict__ swp)
{
  const int b = blockIdx.x, kc = blockIdx.y;   // (16,16): 128 k-rows each
  const int t = threadIdx.x;
  const int chunk = t % 96, rg = t / 96;
  const __bf16* xr = xb + ((size_t)b * Tn + (size_t)kc * 128) * 768;
  const float*  wr = wsum + (size_t)b * Tn + (size_t)kc * 128;
  float acc[8] = {};
  float swl = 0.f;
  for (int k2 = 0; k2 < 64; ++k2) {
    const int k = k2 * 2 + rg;
    const float wk = wr[k];
    const bf16x8 v8 = *(const bf16x8*)&xr[(size_t)k * 768 + chunk * 8];
    if (chunk == 0) swl += wk;
#pragma unroll
    for (int j = 0; j < 8; ++j) acc[j] += wk * (float)v8[j];
  }
  float* yb = y + (size_t)b * 768 + chunk * 8;
#pragma unroll
  for (int j = 0; j < 8; ++j) atomicAdd(yb + j, acc[j]);
  if (chunk == 0) atomicAdd(&swp[b], swl);
}

// ---------------- out_pre[b,d] = ( y[b,:].Wv[d,:] + sw[b]*bv[d] ) / T
__global__ __launch_bounds__(256)
void vproj_kernel(const float* __restrict__ y, const float* __restrict__ swp,
                  const float* __restrict__ Wv, const float* __restrict__ bv,
                  float* __restrict__ opre)
{
  __shared__ float ys[768];
  const int b = blockIdx.x, dg = blockIdx.y, t = threadIdx.x;
  for (int i = t; i < 768; i += 256) ys[i] = y[(size_t)b * 768 + i];
  __syncthreads();
  const float sw = swp[b];
  const int d = dg * 256 + t;
  const float4v* wrow = (const float4v*)(Wv + (size_t)d * 768);
  const float4v* ysv  = (const float4v*)ys;
  float4v a = {};
  for (int c = 0; c < 192; ++c) {
    const float4v wv4 = wrow[c];
    const float4v yv4 = ysv[c];
#pragma unroll
    for (int j = 0; j < 4; ++j) a[j] += wv4[j] * yv4[j];
  }
  const float dot = a[0] + a[1] + a[2] + a[3];
  opre[(size_t)b * 768 + d] = (dot + sw * bv[d]) * (1.f / 2048.f);
}

// ---------------- BatchNorm1d over batch dim
__global__ void bn_kernel(const float* __restrict__ out_pre,
                          const float* __restrict__ gamma, const float* __restrict__ beta,
                          float* __restrict__ out)
{
  const int d = blockIdx.x * 256 + threadIdx.x;
  float vals[16];
  float s = 0.f;
#pragma unroll
  for (int b = 0; b < 16; ++b) { vals[b] = out_pre[b * Cn + d]; s += vals[b]; }
  const float mu = s * (1.f / 16.f);
  float s2 = 0.f;
#pragma unroll
  for (int b = 0; b < 16; ++b) { float t2 = vals[b] - mu; s2 += t2 * t2; }
  const float inv = rsqrtf(s2 * (1.f / 16.f) + 1e-5f);
  const float g = gamma[d] * inv, be = beta[d];
#pragma unroll
  for (int b = 0; b < 16; ++b) out[b * Cn + d] = (vals[b] - mu) * g + be;
}

extern "C" void kernel_launch(void* const* d_in, const int* in_sizes, int n_in,
                              void* d_out, int out_size, void* d_ws, size_t ws_size,
                              hipStream_t stream)
{
  const float* x  = (const float*)d_in[0];
  const float* Wq = (const float*)d_in[1];
  const float* bq = (const float*)d_in[2];
  const float* Wk = (const float*)d_in[3];
  const float* bk = (const float*)d_in[4];
  const float* Wv = (const float*)d_in[5];
  const float* bv = (const float*)d_in[6];
  const float* gamma = (const float*)d_in[7];
  const float* beta  = (const float*)d_in[8];
  float* out = (float*)d_out;

  char* ws = (char*)d_ws;
  // workspace layout (~97.6 MiB)
  __hip_bfloat16* xb  = (__hip_bfloat16*)(ws);                  // 50,331,648
  __hip_bfloat16* Zb  = (__hip_bfloat16*)(ws + 50331648);       // 50,331,648
  __bf16*         Gt  = (__bf16*)        (ws + 100663296);      //  1,179,648
  float*          u   = (float*)         (ws + 101842944);      //    131,072
  float*          v   = (float*)         (ws + 101974016);      //    131,072
  float*          wsum= (float*)         (ws + 102105088);      //    131,072  <- zero from here
  float*          yv  = (float*)         (ws + 102236160);      //     49,152
  float*          wqbk= (float*)         (ws + 102285312);      //      3,072
  float*          wkbq= (float*)         (ws + 102288384);      //      3,072
  float*          c0p = (float*)         (ws + 102291456);      //         64
  float*          swp = (float*)         (ws + 102291520);      //         64
  float*          opre= (float*)         (ws + 102291584);      //     49,152

  (void)in_sizes; (void)n_in; (void)out_size; (void)ws_size;

  // zero wsum + yv + wqbk + wkbq + c0 + sw (contiguous)
  hipMemsetAsync(wsum, 0, 131072 + 49152 + 3072 + 3072 + 64 + 64, stream);

  biasprep<<<dim3(3, 33), 256, 0, stream>>>(Wq, Wk, bq, bk, wqbk, wkbq, c0p);
  gt_kernel<<<dim3(144), 256, 0, stream>>>(Wk, Wq, Gt);
  cvt_x_uv<<<dim3(4096), 512, 0, stream>>>(x, wqbk, wkbq, c0p, xb, u, v);

  z_kernel<<<dim3(256), 512, 0, stream>>>((const __bf16*)xb, Gt, Zb);

  attn_kernel<<<dim3(256), 512, 0, stream>>>(
      (const __bf16*)Zb, (const __bf16*)xb, u, v, wsum);

  wx_kernel<<<dim3(16, 16), 192, 0, stream>>>(wsum, (const __bf16*)xb, yv, swp);
  vproj_kernel<<<dim3(16, 3), 256, 0, stream>>>(yv, swp, Wv, bv, opre);
  bn_kernel<<<dim3(3), 256, 0, stream>>>(opre, gamma, beta, out);
}